// Round 1
// baseline (633.774 us; speedup 1.0000x reference)
//
#include <hip/hip_runtime.h>

constexpr int NN = 50000;
constexpr int NE = 1600000;
constexpr int NG = 1000;

// workspace layout (float offsets). Zero-initialized prefix first.
constexpr int OFF_AGGR1 = 0;            // NN*8  = 400000 (stride 8, 7 used)
constexpr int OFF_AGGR2 = 400000;       // NN*64 = 3200000
constexpr int OFF_SUMS  = 3600000;      // NG*64 = 64000
constexpr int OFF_CNT   = 3664000;      // NG    = 1000
constexpr int ZERO_FLOATS = 3665000;    // memset everything above
constexpr int OFF_H1    = 3670016;      // NN*64 (no zero needed), 64-aligned

// ---------------- Layer 1 edge pass: msg = relu(x[src] + ea@We1+be1); atomic scatter to aggr1[dst]
__global__ __launch_bounds__(256) void edge1_kernel(
    const float* __restrict__ x, const float* __restrict__ edge_attr,
    const int* __restrict__ eidx, const float* __restrict__ We1,
    const float* __restrict__ be1, float* __restrict__ aggr1)
{
    __shared__ float sW[4][8];
    __shared__ float sb[8];
    if (threadIdx.x < 32) {
        int k = threadIdx.x >> 3, d = threadIdx.x & 7;
        sW[k][d] = (d < 7) ? We1[k * 7 + d] : 0.f;
        if (k == 0) sb[d] = (d < 7) ? be1[d] : 0.f;
    }
    __syncthreads();
    int tid = blockIdx.x * blockDim.x + threadIdx.x;
    int total = NE * 8;
    int stride = gridDim.x * blockDim.x;
    for (int i = tid; i < total; i += stride) {
        int e = i >> 3, d = i & 7;
        if (d == 7) continue;
        const float4 ea = *(const float4*)(edge_attr + (size_t)e * 4);
        int src = eidx[e];
        int dst = eidx[NE + e];
        float v = sb[d] + ea.x * sW[0][d] + ea.y * sW[1][d] + ea.z * sW[2][d] + ea.w * sW[3][d]
                + x[(size_t)src * 7 + d];
        v = fmaxf(v, 0.f);
        atomicAdd(aggr1 + (size_t)dst * 8 + d, v);
    }
}

// ---------------- Layer 1 node MLP: h1 = relu( relu((x+aggr1)@W1a+b1a) @ W1b + b1b )
// one wave per node, lane = output dim; cross-lane via per-wave LDS (wave64 lockstep)
__global__ __launch_bounds__(256) void node1_kernel(
    const float* __restrict__ x, const float* __restrict__ aggr1,
    const float* __restrict__ W1a, const float* __restrict__ b1a,
    const float* __restrict__ W1b, const float* __restrict__ b1b,
    float* __restrict__ h1)
{
    __shared__ float sWa[7 * 64];
    __shared__ float sWb[64 * 64];
    __shared__ float sba[64];
    __shared__ float sbb[64];
    __shared__ float tbuf[4][64];
    for (int i = threadIdx.x; i < 7 * 64; i += 256) sWa[i] = W1a[i];
    for (int i = threadIdx.x; i < 64 * 64; i += 256) sWb[i] = W1b[i];
    if (threadIdx.x < 64) { sba[threadIdx.x] = b1a[threadIdx.x]; sbb[threadIdx.x] = b1b[threadIdx.x]; }
    __syncthreads();
    const int w = threadIdx.x >> 6;
    const int d = threadIdx.x & 63;
    const int slot = blockIdx.x * 4 + w;
    const int nslots = gridDim.x * 4;
    for (int node = slot; node < NN; node += nslots) {
        float z[7];
        #pragma unroll
        for (int k = 0; k < 7; ++k)
            z[k] = x[(size_t)node * 7 + k] + aggr1[(size_t)node * 8 + k];
        float t = sba[d];
        #pragma unroll
        for (int k = 0; k < 7; ++k) t += z[k] * sWa[k * 64 + d];
        t = fmaxf(t, 0.f);
        tbuf[w][d] = t;   // per-wave buffer: wave64 lockstep, no barrier needed
        float o = sbb[d];
        #pragma unroll 8
        for (int k = 0; k < 64; ++k) o += tbuf[w][k] * sWb[k * 64 + d];
        o = fmaxf(o, 0.f);
        h1[(size_t)node * 64 + d] = o;
    }
}

// ---------------- Layer 2 edge pass: one wave per edge, lane = dim
__global__ __launch_bounds__(256) void edge2_kernel(
    const float* __restrict__ h1, const float* __restrict__ edge_attr,
    const int* __restrict__ eidx, const float* __restrict__ We2,
    const float* __restrict__ be2, float* __restrict__ aggr2)
{
    __shared__ float sW[4 * 64];
    __shared__ float sb[64];
    for (int i = threadIdx.x; i < 256; i += 256) sW[i] = We2[i];
    if (threadIdx.x < 64) sb[threadIdx.x] = be2[threadIdx.x];
    __syncthreads();
    const int d = threadIdx.x & 63;
    const int wv = (blockIdx.x * blockDim.x + threadIdx.x) >> 6;
    const int nw = (gridDim.x * blockDim.x) >> 6;
    for (int e = wv; e < NE; e += nw) {
        const float4 ea = *(const float4*)(edge_attr + (size_t)e * 4);   // broadcast
        int src = eidx[e];
        int dst = eidx[NE + e];
        float v = sb[d] + ea.x * sW[d] + ea.y * sW[64 + d] + ea.z * sW[128 + d] + ea.w * sW[192 + d]
                + h1[(size_t)src * 64 + d];                              // coalesced 256B gather
        v = fmaxf(v, 0.f);
        atomicAdd(aggr2 + (size_t)dst * 64 + d, v);                      // contiguous-address atomics
    }
}

// ---------------- Layer 2 node MLP + fused global-mean-pool accumulation
__global__ __launch_bounds__(256) void node2_kernel(
    const float* __restrict__ h1, const float* __restrict__ aggr2,
    const float* __restrict__ W2a, const float* __restrict__ b2a,
    const float* __restrict__ W2b, const float* __restrict__ b2b,
    const int* __restrict__ batch,
    float* __restrict__ sums, float* __restrict__ cnt)
{
    __shared__ float sWa[64 * 64];
    __shared__ float sWb[64 * 64];
    __shared__ float sba[64];
    __shared__ float sbb[64];
    __shared__ float zbuf[4][64];
    __shared__ float tbuf[4][64];
    for (int i = threadIdx.x; i < 64 * 64; i += 256) { sWa[i] = W2a[i]; sWb[i] = W2b[i]; }
    if (threadIdx.x < 64) { sba[threadIdx.x] = b2a[threadIdx.x]; sbb[threadIdx.x] = b2b[threadIdx.x]; }
    __syncthreads();
    const int w = threadIdx.x >> 6;
    const int d = threadIdx.x & 63;
    const int slot = blockIdx.x * 4 + w;
    const int nslots = gridDim.x * 4;
    for (int node = slot; node < NN; node += nslots) {
        float zd = h1[(size_t)node * 64 + d] + aggr2[(size_t)node * 64 + d];
        zbuf[w][d] = zd;
        float t = sba[d];
        #pragma unroll 8
        for (int k = 0; k < 64; ++k) t += zbuf[w][k] * sWa[k * 64 + d];
        t = fmaxf(t, 0.f);
        tbuf[w][d] = t;
        float o = sbb[d];
        #pragma unroll 8
        for (int k = 0; k < 64; ++k) o += tbuf[w][k] * sWb[k * 64 + d];
        o = fmaxf(o, 0.f);                    // h2 never materialized
        int g = batch[node];
        atomicAdd(sums + (size_t)g * 64 + d, o);
        if (d == 0) atomicAdd(cnt + g, 1.0f);
    }
}

// ---------------- Final: out[g][j] = (sums[g]/max(cnt,1)) @ Wfc + bfc
__global__ __launch_bounds__(256) void fc_kernel(
    const float* __restrict__ sums, const float* __restrict__ cnt,
    const float* __restrict__ Wfc, const float* __restrict__ bfc,
    float* __restrict__ out)
{
    int gid = blockIdx.x * blockDim.x + threadIdx.x;
    if (gid >= NG * 12) return;
    int g = gid / 12, j = gid - g * 12;
    float inv = 1.f / fmaxf(cnt[g], 1.f);
    float acc = bfc[j];
    #pragma unroll 8
    for (int k = 0; k < 64; ++k) acc += sums[(size_t)g * 64 + k] * inv * Wfc[k * 12 + j];
    out[gid] = acc;
}

extern "C" void kernel_launch(void* const* d_in, const int* in_sizes, int n_in,
                              void* d_out, int out_size, void* d_ws, size_t ws_size,
                              hipStream_t stream)
{
    (void)in_sizes; (void)n_in; (void)out_size; (void)ws_size;
    const float* x    = (const float*)d_in[0];
    const float* ea   = (const float*)d_in[1];
    const int*   eidx = (const int*)d_in[2];
    const int*   batch= (const int*)d_in[3];
    const float* We1  = (const float*)d_in[4];
    const float* be1  = (const float*)d_in[5];
    const float* W1a  = (const float*)d_in[6];
    const float* b1a  = (const float*)d_in[7];
    const float* W1b  = (const float*)d_in[8];
    const float* b1b  = (const float*)d_in[9];
    const float* We2  = (const float*)d_in[10];
    const float* be2  = (const float*)d_in[11];
    const float* W2a  = (const float*)d_in[12];
    const float* b2a  = (const float*)d_in[13];
    const float* W2b  = (const float*)d_in[14];
    const float* b2b  = (const float*)d_in[15];
    const float* Wfc  = (const float*)d_in[16];
    const float* bfc  = (const float*)d_in[17];
    float* out = (float*)d_out;
    float* ws  = (float*)d_ws;

    float* aggr1 = ws + OFF_AGGR1;
    float* aggr2 = ws + OFF_AGGR2;
    float* sums  = ws + OFF_SUMS;
    float* cnt   = ws + OFF_CNT;
    float* h1    = ws + OFF_H1;

    hipMemsetAsync(d_ws, 0, (size_t)ZERO_FLOATS * sizeof(float), stream);

    edge1_kernel<<<50000, 256, 0, stream>>>(x, ea, eidx, We1, be1, aggr1);
    node1_kernel<<<1250, 256, 0, stream>>>(x, aggr1, W1a, b1a, W1b, b1b, h1);
    edge2_kernel<<<2048, 256, 0, stream>>>(h1, ea, eidx, We2, be2, aggr2);
    node2_kernel<<<1250, 256, 0, stream>>>(h1, aggr2, W2a, b2a, W2b, b2b, batch, sums, cnt);
    fc_kernel<<<(NG * 12 + 255) / 256, 256, 0, stream>>>(sums, cnt, Wfc, bfc, out);
}